// Round 3
// baseline (224.889 us; speedup 1.0000x reference)
//
#include <hip/hip_runtime.h>
#include <hip/hip_bf16.h>
#include <math.h>

// FSCILGate: gates = softmax(x @ q^T / T) [200704 x 16] + scalar aux loss.
// HBM floor: 411 MB read + 12.8 MB write @ ~6.5 TB/s -> ~65 us.
//
// One wave per 16-row tile via mfma_f32_16x16x32_bf16 with SWAPPED operands:
// A = q fragments (built once/wave), B = x fragments (loaded direct from
// global in fragment layout, row=lane&15, k=(lane>>4)*8 -- each 128B line
// fully consumed by the 4 k-group lanes). C/D layout (HW-verified:
// col=lane&15, row=(lane>>4)*4+reg) then gives:
//   lane holds logits for row R=lane&15, experts E=(lane>>4)*4+r, r=0..3.
// => softmax/top-2 over experts = 3-op in-register tree + 2 shuffles
//    (xor 16/32), computed once per row (no duplication), and the gate
//    store is one coalesced float4 per lane (wave covers contiguous 1KB).
//
// Occupancy: launch_bounds(256,4) caps 128 VGPR (aq=64 + acc + stats + load
// buffering) -> 16 waves/CU; TLP hides HBM latency. Tiles come from an
// atomic work queue (counter in ws) -> perfect CU balance.

#define NROWS 200704  // 64*56*56
#define DDIM 512
#define NEXP 16
#define KSTEPS 16     // 512 / 32
#define NTILES (NROWS / 16)  // 12544
#define NBLOCKS 1024         // 4 blocks/CU resident, persistent + queue

typedef __attribute__((ext_vector_type(8))) short short8;
typedef __attribute__((ext_vector_type(4))) float f32x4;

static __device__ inline short f2bf(float f) {
    __bf16 h = (__bf16)f;  // RTNE; compiler pairs into v_cvt_pk_bf16_f32
    return __builtin_bit_cast(short, h);
}

static __device__ inline short8 pack8(float4 a, float4 b) {
    short8 r;
    r[0] = f2bf(a.x); r[1] = f2bf(a.y); r[2] = f2bf(a.z); r[3] = f2bf(a.w);
    r[4] = f2bf(b.x); r[5] = f2bf(b.y); r[6] = f2bf(b.z); r[7] = f2bf(b.w);
    return r;
}

__global__ __launch_bounds__(256, 4) void gate_kernel(
    const float* __restrict__ x,
    const float* __restrict__ q,
    const float* __restrict__ temp,
    float* __restrict__ out,
    float* __restrict__ ws)
{
    const int lane = threadIdx.x & 63;
    const int fe = lane & 15;  // fragment row index (A: expert; B: tile row)
    const int g  = lane >> 4;  // k-group
    int* qcnt = (int*)ws + 32;

    const float invT = 1.0f / temp[0];

    // A fragments: q[fe][k], k = g*8 + s*32 .. +8, as bf16. 64 VGPRs, once.
    short8 aq[KSTEPS];
    {
        const float* qp = q + fe * DDIM + g * 8;
#pragma unroll
        for (int s = 0; s < KSTEPS; ++s) {
            float4 a = *reinterpret_cast<const float4*>(qp + s * 32);
            float4 b = *reinterpret_cast<const float4*>(qp + s * 32 + 4);
            aq[s] = pack8(a, b);
        }
    }

    float sS[4] = {0, 0, 0, 0};  // gate-score sums for experts g*4+r
    float sC[4] = {0, 0, 0, 0};  // top-2 counts for experts g*4+r

    for (;;) {
        int t = 0;
        if (lane == 0) t = atomicAdd(qcnt, 1);
        t = __shfl(t, 0, 64);
        if (t >= NTILES) break;

        // B fragments: x[t*16 + fe][k], k = g*8 + s*32 .. +8.
        const float* xr = x + (size_t)t * 16 * DDIM + (size_t)fe * DDIM + g * 8;
        f32x4 acc = {0.0f, 0.0f, 0.0f, 0.0f};
#pragma unroll
        for (int s = 0; s < KSTEPS; ++s) {
            float4 a = *reinterpret_cast<const float4*>(xr + s * 32);
            float4 b = *reinterpret_cast<const float4*>(xr + s * 32 + 4);
            acc = __builtin_amdgcn_mfma_f32_16x16x32_bf16(aq[s], pack8(a, b),
                                                          acc, 0, 0, 0);
        }

        // lane: row R = fe, logits for experts E = g*4 + r.
        const float l0 = acc[0] * invT, l1 = acc[1] * invT;
        const float l2 = acc[2] * invT, l3 = acc[3] * invT;

        float m = fmaxf(fmaxf(l0, l1), fmaxf(l2, l3));
        m = fmaxf(m, __shfl_xor(m, 16, 64));
        m = fmaxf(m, __shfl_xor(m, 32, 64));

        const float p0 = __expf(l0 - m), p1 = __expf(l1 - m);
        const float p2 = __expf(l2 - m), p3 = __expf(l3 - m);
        float s4 = (p0 + p1) + (p2 + p3);
        s4 += __shfl_xor(s4, 16, 64);
        s4 += __shfl_xor(s4, 32, 64);
        const float inv = 1.0f / s4;
        const float g0 = p0 * inv, g1 = p1 * inv, g2 = p2 * inv, g3 = p3 * inv;

        // second max (mask all top-1 instances)
        const float NI = -3.4e38f;
        const float M0 = (l0 == m) ? NI : l0, M1 = (l1 == m) ? NI : l1;
        const float M2 = (l2 == m) ? NI : l2, M3 = (l3 == m) ? NI : l3;
        float m2 = fmaxf(fmaxf(M0, M1), fmaxf(M2, M3));
        m2 = fmaxf(m2, __shfl_xor(m2, 16, 64));
        m2 = fmaxf(m2, __shfl_xor(m2, 32, 64));

        sS[0] += g0; sS[1] += g1; sS[2] += g2; sS[3] += g3;
        sC[0] += (l0 >= m2) ? 1.0f : 0.0f;
        sC[1] += (l1 >= m2) ? 1.0f : 0.0f;
        sC[2] += (l2 >= m2) ? 1.0f : 0.0f;
        sC[3] += (l3 >= m2) ? 1.0f : 0.0f;

        float4 o = make_float4(g0, g1, g2, g3);
        *reinterpret_cast<float4*>(out + ((size_t)t * 16 + fe) * NEXP + g * 4) = o;
    }

    // Fold stats across the 16 rows (lane bits 0..3), once per wave.
#pragma unroll
    for (int r = 0; r < 4; ++r) {
        sS[r] += __shfl_xor(sS[r], 1, 64);
        sS[r] += __shfl_xor(sS[r], 2, 64);
        sS[r] += __shfl_xor(sS[r], 4, 64);
        sS[r] += __shfl_xor(sS[r], 8, 64);
        sC[r] += __shfl_xor(sC[r], 1, 64);
        sC[r] += __shfl_xor(sC[r], 2, 64);
        sC[r] += __shfl_xor(sC[r], 4, 64);
        sC[r] += __shfl_xor(sC[r], 8, 64);
    }

    __shared__ float sred[32];
    if (threadIdx.x < 32) sred[threadIdx.x] = 0.0f;
    __syncthreads();
    if (fe == 0) {
#pragma unroll
        for (int r = 0; r < 4; ++r) {
            atomicAdd(&sred[g * 4 + r], sS[r]);
            atomicAdd(&sred[16 + g * 4 + r], sC[r]);
        }
    }
    __syncthreads();
    if (threadIdx.x < 32) atomicAdd(&ws[threadIdx.x], sred[threadIdx.x]);
}

// aux = 0.01 * mean_e(avg_e * load_e) * 256 = 0.08 * sum_e(S_e * C_e) / N^2
__global__ void aux_kernel(const float* __restrict__ ws, float* __restrict__ out) {
    if (threadIdx.x == 0 && blockIdx.x == 0) {
        float a = 0.0f;
#pragma unroll
        for (int e = 0; e < NEXP; ++e) a += ws[e] * ws[16 + e];
        const float n = (float)NROWS;
        out[(size_t)NROWS * NEXP] = 0.08f * a / (n * n);
    }
}

extern "C" void kernel_launch(void* const* d_in, const int* in_sizes, int n_in,
                              void* d_out, int out_size, void* d_ws, size_t ws_size,
                              hipStream_t stream) {
    const float* x = (const float*)d_in[0];
    const float* q = (const float*)d_in[1];
    const float* t = (const float*)d_in[2];
    float* out = (float*)d_out;
    float* ws = (float*)d_ws;

    hipMemsetAsync(ws, 0, 33 * sizeof(float), stream);  // 32 stats + queue ctr
    gate_kernel<<<NBLOCKS, 256, 0, stream>>>(x, q, t, out, ws);
    aux_kernel<<<1, 64, 0, stream>>>(ws, out);
}

// Round 4
// 102.441 us; speedup vs baseline: 2.1953x; 2.1953x over previous
//
#include <hip/hip_runtime.h>
#include <hip/hip_bf16.h>
#include <math.h>

// FSCILGate: gates = softmax(x @ q^T / T) [200704 x 16] + scalar aux loss.
// HBM floor: 411 MB read + 12.8 MB write @ ~6.5 TB/s -> ~65 us.
//
// One wave per 16-row tile, mfma_f32_16x16x32_bf16, SWAPPED operands
// (A = q fragments, B = x fragments): C/D layout (col=lane&15,
// row=(lane>>4)*4+reg) gives lane -> (row fe=lane&15, experts (lane>>4)*4+r).
// Softmax/top-2 over experts = in-register tree + 2 shuffles (xor16/32),
// gate store = one coalesced float4/lane (wave covers contiguous 1KB).
//
// R3 post-mortem fixes:
//  - NO atomic work queue (same-address cross-XCD atomics serialized R3).
//    Static partition: 784 blocks x 4 waves = 3136 waves x exactly 4
//    contiguous tiles (128KB sequential stream per wave). Zero imbalance.
//  - q fragments live in LDS (16KB/block, built once, shared by 4 waves;
//    ds_read_b128 of contiguous 1KB/step = conflict-free) instead of 64
//    VGPRs -> fits __launch_bounds__(256,4) without spills -> 16 waves/CU
//    to smooth HBM demand (R2's 3.6 TB/s was a TLP/demand-gap limit).

#define NROWS 200704  // 64*56*56
#define DDIM 512
#define NEXP 16
#define KSTEPS 16                 // 512 / 32
#define NTILES (NROWS / 16)       // 12544
#define NBLOCKS 784               // 3136 waves * 4 tiles = 12544 exact
#define TILES_PER_WAVE 4

typedef __attribute__((ext_vector_type(8))) short short8;
typedef __attribute__((ext_vector_type(4))) float f32x4;

static __device__ inline short f2bf(float f) {
    __bf16 h = (__bf16)f;  // RTNE; compiler pairs into v_cvt_pk_bf16_f32
    return __builtin_bit_cast(short, h);
}

static __device__ inline short8 pack8(float4 a, float4 b) {
    short8 r;
    r[0] = f2bf(a.x); r[1] = f2bf(a.y); r[2] = f2bf(a.z); r[3] = f2bf(a.w);
    r[4] = f2bf(b.x); r[5] = f2bf(b.y); r[6] = f2bf(b.z); r[7] = f2bf(b.w);
    return r;
}

__global__ __launch_bounds__(256, 4) void gate_kernel(
    const float* __restrict__ x,
    const float* __restrict__ q,
    const float* __restrict__ temp,
    float* __restrict__ out,
    float* __restrict__ ws)
{
    const int lane = threadIdx.x & 63;
    const int wid  = threadIdx.x >> 6;
    const int gwave = blockIdx.x * 4 + wid;
    const int fe = lane & 15;  // fragment index (A: expert row; B: tile row)
    const int g  = lane >> 4;  // k-group

    // q fragments in LDS, one copy per block: slot idx = s*64 + lane.
    __shared__ short8 qlds[KSTEPS * 64];  // 16 KB
    {
        for (int idx = threadIdx.x; idx < KSTEPS * 64; idx += 256) {
            const int s = idx >> 6, ln = idx & 63;
            const int qfe = ln & 15, qg = ln >> 4;
            const float* qp = q + qfe * DDIM + qg * 8 + s * 32;
            float4 a = *reinterpret_cast<const float4*>(qp);
            float4 b = *reinterpret_cast<const float4*>(qp + 4);
            qlds[idx] = pack8(a, b);
        }
    }
    __syncthreads();

    const float invT = 1.0f / temp[0];

    float sS[4] = {0, 0, 0, 0};  // gate-score sums for experts g*4+r
    float sC[4] = {0, 0, 0, 0};  // top-2 counts for experts g*4+r

    const int t0 = gwave * TILES_PER_WAVE;
#pragma unroll 1
    for (int t = t0; t < t0 + TILES_PER_WAVE; ++t) {
        // B fragments: x[t*16 + fe][k], k = g*8 + s*32 .. +8, direct from HBM.
        const float* xr = x + (size_t)t * 16 * DDIM + (size_t)fe * DDIM + g * 8;
        f32x4 acc = {0.0f, 0.0f, 0.0f, 0.0f};
#pragma unroll
        for (int s = 0; s < KSTEPS; ++s) {
            float4 a = *reinterpret_cast<const float4*>(xr + s * 32);
            float4 b = *reinterpret_cast<const float4*>(xr + s * 32 + 4);
            acc = __builtin_amdgcn_mfma_f32_16x16x32_bf16(
                qlds[s * 64 + lane], pack8(a, b), acc, 0, 0, 0);
        }

        // lane: row R = fe, logits for experts E = g*4 + r.
        const float l0 = acc[0] * invT, l1 = acc[1] * invT;
        const float l2 = acc[2] * invT, l3 = acc[3] * invT;

        float m = fmaxf(fmaxf(l0, l1), fmaxf(l2, l3));
        m = fmaxf(m, __shfl_xor(m, 16, 64));
        m = fmaxf(m, __shfl_xor(m, 32, 64));

        const float p0 = __expf(l0 - m), p1 = __expf(l1 - m);
        const float p2 = __expf(l2 - m), p3 = __expf(l3 - m);
        float s4 = (p0 + p1) + (p2 + p3);
        s4 += __shfl_xor(s4, 16, 64);
        s4 += __shfl_xor(s4, 32, 64);
        const float inv = 1.0f / s4;
        const float g0 = p0 * inv, g1 = p1 * inv, g2 = p2 * inv, g3 = p3 * inv;

        // second max (mask all top-1 instances)
        const float NI = -3.4e38f;
        const float M0 = (l0 == m) ? NI : l0, M1 = (l1 == m) ? NI : l1;
        const float M2 = (l2 == m) ? NI : l2, M3 = (l3 == m) ? NI : l3;
        float m2 = fmaxf(fmaxf(M0, M1), fmaxf(M2, M3));
        m2 = fmaxf(m2, __shfl_xor(m2, 16, 64));
        m2 = fmaxf(m2, __shfl_xor(m2, 32, 64));

        sS[0] += g0; sS[1] += g1; sS[2] += g2; sS[3] += g3;
        sC[0] += (l0 >= m2) ? 1.0f : 0.0f;
        sC[1] += (l1 >= m2) ? 1.0f : 0.0f;
        sC[2] += (l2 >= m2) ? 1.0f : 0.0f;
        sC[3] += (l3 >= m2) ? 1.0f : 0.0f;

        float4 o = make_float4(g0, g1, g2, g3);
        *reinterpret_cast<float4*>(out + ((size_t)t * 16 + fe) * NEXP + g * 4) = o;
    }

    // Fold stats across the 16 rows (lane bits 0..3), once per wave.
#pragma unroll
    for (int r = 0; r < 4; ++r) {
        sS[r] += __shfl_xor(sS[r], 1, 64);
        sS[r] += __shfl_xor(sS[r], 2, 64);
        sS[r] += __shfl_xor(sS[r], 4, 64);
        sS[r] += __shfl_xor(sS[r], 8, 64);
        sC[r] += __shfl_xor(sC[r], 1, 64);
        sC[r] += __shfl_xor(sC[r], 2, 64);
        sC[r] += __shfl_xor(sC[r], 4, 64);
        sC[r] += __shfl_xor(sC[r], 8, 64);
    }

    __shared__ float sred[32];
    if (threadIdx.x < 32) sred[threadIdx.x] = 0.0f;
    __syncthreads();
    if (fe == 0) {
#pragma unroll
        for (int r = 0; r < 4; ++r) {
            atomicAdd(&sred[g * 4 + r], sS[r]);
            atomicAdd(&sred[16 + g * 4 + r], sC[r]);
        }
    }
    __syncthreads();
    if (threadIdx.x < 32) atomicAdd(&ws[threadIdx.x], sred[threadIdx.x]);
}

// aux = 0.01 * mean_e(avg_e * load_e) * 256 = 0.08 * sum_e(S_e * C_e) / N^2
__global__ void aux_kernel(const float* __restrict__ ws, float* __restrict__ out) {
    if (threadIdx.x == 0 && blockIdx.x == 0) {
        float a = 0.0f;
#pragma unroll
        for (int e = 0; e < NEXP; ++e) a += ws[e] * ws[16 + e];
        const float n = (float)NROWS;
        out[(size_t)NROWS * NEXP] = 0.08f * a / (n * n);
    }
}

extern "C" void kernel_launch(void* const* d_in, const int* in_sizes, int n_in,
                              void* d_out, int out_size, void* d_ws, size_t ws_size,
                              hipStream_t stream) {
    const float* x = (const float*)d_in[0];
    const float* q = (const float*)d_in[1];
    const float* t = (const float*)d_in[2];
    float* out = (float*)d_out;
    float* ws = (float*)d_ws;

    hipMemsetAsync(ws, 0, 32 * sizeof(float), stream);
    gate_kernel<<<NBLOCKS, 256, 0, stream>>>(x, q, t, out, ws);
    aux_kernel<<<1, 64, 0, stream>>>(ws, out);
}